// Round 12
// baseline (274.765 us; speedup 1.0000x reference)
//
#include <hip/hip_runtime.h>

typedef unsigned short u16;
typedef unsigned int u32;
typedef __attribute__((ext_vector_type(2))) u32 u32x2;
typedef __attribute__((ext_vector_type(4))) u32 u32x4;
typedef __attribute__((ext_vector_type(2))) float f32x2;
typedef __attribute__((ext_vector_type(4))) float f32x4;
typedef __attribute__((ext_vector_type(8))) short s16x8;

#define DEV __device__ __forceinline__

DEV float bflo(u32 u){ union{u32 i; float f;} c; c.i = u << 16; return c.f; }
DEV float bfhi(u32 u){ union{u32 i; float f;} c; c.i = u & 0xffff0000u; return c.f; }
DEV u16 f2b(float f){
  union{float f; u32 u;} c; c.f = f;
  u32 u = c.u;
  u32 r = (u + 0x7fffu + ((u >> 16) & 1u)) >> 16;
  return (u16)r;
}
DEV float fsilu(float v){ return v / (1.f + __expf(-v)); }

// async global->LDS DMA, 16B per lane; LDS dest = wave-uniform base + lane*16
typedef const __attribute__((address_space(1))) u32 gu32;
typedef __attribute__((address_space(3))) u32 lu32;
DEV void gload16(const u32* g, u32* l) {
  __builtin_amdgcn_global_load_lds((gu32*)g, (lu32*)l, 16, 0, 0);
}

constexpr int Bn = 32, Cin = 64, H = 56, Wd = 56, HID = 384, CO = 64;
constexpr int HW = H * Wd;            // 3136
constexpr float EPS = 1e-5f;

constexpr int WTAP = 128 * 64;
constexpr int WOCT = 9 * WTAP;
constexpr int XTROW = 64 * 64;        // xt/sB row = 64 slots x 64 ic (8KB)
constexpr int PWP = 392;              // sAw row pitch (u16) — bank-safe

// ---------------------------------------------------------------------------
// P1: pack expand weights -> wt (swizzled) + BN1/BN3 scale-shift (block 864).
// ---------------------------------------------------------------------------
__global__ __launch_bounds__(256) void k_prep_wbn(
    const float* __restrict__ w,
    const float* __restrict__ g1, const float* __restrict__ b1,
    const float* __restrict__ m1, const float* __restrict__ v1,
    const float* __restrict__ g3, const float* __restrict__ b3,
    const float* __restrict__ m3, const float* __restrict__ v3,
    u16* __restrict__ wt,
    float* __restrict__ sc1, float* __restrict__ sh1,
    float* __restrict__ sc3, float* __restrict__ sh3)
{
  const int blk = blockIdx.x;
  if (blk < 864) {
    int t = blk * 256 + threadIdx.x;
    int octile = t / WOCT, r = t - octile * WOCT;
    int tap = r / WTAP, r2 = r - tap * WTAP;
    int ocl = r2 >> 6, col = r2 & 63;
    int physo = col >> 3, j = col & 7;
    int olog = physo ^ (ocl & 7);
    int ic = olog * 8 + j;
    int oc = octile * 128 + ocl;
    wt[t] = f2b(w[(oc * Cin + ic) * 9 + tap]);
  } else {
    for (int t = threadIdx.x; t < HID; t += 256) {
      float sc = g1[t] * rsqrtf(v1[t] + EPS);
      sc1[t] = sc;
      sh1[t] = b1[t] - m1[t] * sc;
    }
    if (threadIdx.x < CO) {
      int t = threadIdx.x;
      float sc = g3[t] * rsqrtf(v3[t] + EPS);
      sc3[t] = sc;
      sh3[t] = b3[t] - m3[t] * sc;
    }
  }
}

// ---------------------------------------------------------------------------
// P2: x -> xt bf16 swizzled [b][row 58][slot 64][ic 64].
// row = y+1; rows 0 and 57 zero halo; slots 0 and 57..63 zero.
// ---------------------------------------------------------------------------
__global__ __launch_bounds__(256) void k_prep_x(
    const float* __restrict__ x, u16* __restrict__ xt, int b0)
{
  const int row = blockIdx.x;         // 0..57
  const int b = blockIdx.y, gb = b0 + b;
  const int tid = threadIdx.x;
  u16* dst = xt + ((size_t)b * 58 + row) * XTROW;
  if (row == 0 || row == 57) {
    for (int i = tid; i < 2048; i += 256) ((u32*)dst)[i] = 0;
    return;
  }
  const int y = row - 1;
  __shared__ u16 sx[64 * 58];         // [ic][px], pitch 58
  {
    const int ic = tid >> 2, seg = tid & 3;
    const float* xp = x + ((size_t)(gb * Cin + ic) * H + y) * Wd + seg * 14;
    #pragma unroll
    for (int t = 0; t < 14; ++t) sx[ic * 58 + seg * 14 + t] = f2b(xp[t]);
  }
  __syncthreads();
  #pragma unroll
  for (int it = 0; it < 16; ++it) {
    const int slot = it * 4 + (tid >> 6);   // 0..63
    const int j = tid & 63;
    u16 v = 0;
    if (slot >= 1 && slot <= 56) {
      int ic = (((j >> 3) ^ (slot & 7)) << 3) | (j & 7);
      v = sx[ic * 58 + (slot - 1)];
    }
    dst[slot * 64 + j] = v;           // 128B contiguous per wave-slot
  }
}

// ---------------------------------------------------------------------------
// K1 (r22): expand conv MFMA shift-GEMM — 2-rows-per-wave tile.
// Block = 8 output rows, 4 waves x 2 rows; wave tile = 128oc x 64px x 2rows
// (acc 256 VGPR -> launch_bounds(256,1), 1 block/CU, 512-VGPR budget).
// LDS ops/MFMA: 0.4375 -> 0.28 (A-frags reused across both rows); wt L2
// traffic per MFMA halves. LDS = sB 10 xt rows (+pad) 80.3KB + sA dbuf
// 32.8KB = 113KB. Grid 7x32 = 224 blocks (87.5% CU coverage, = r21).
// dbuf sA + T14 register prefetch + 1 barrier/step.
// ---------------------------------------------------------------------------
__global__ __launch_bounds__(256, 1) void k_expand_mfma(
    const u16* __restrict__ xt, const u16* __restrict__ wt,
    const float* __restrict__ sc1, const float* __restrict__ sh1,
    u16* __restrict__ h, int b0)
{
  (void)b0;
  __shared__ u16 sB[10 * XTROW + 128];  // 82,176 B (pad covers slot<=65 reads)
  __shared__ u16 sA[2][WTAP];           // 32,768 B
  const int tid = threadIdx.x;
  const int yo = blockIdx.x, b = blockIdx.y;
  const int y0 = yo * 8;
  const int wave = tid >> 6, ln = tid & 63;
  const int lane15 = ln & 15, quad = ln >> 4;

  // prologue staging: sB (10 xt rows = input y0-1..y0+8) + sA[0], all DMA
  {
    const u32* xsrc = (const u32*)(xt + ((size_t)b * 58 + y0) * XTROW);
    #pragma unroll
    for (int it = 0; it < 20; ++it) {
      int chunk = it * 256 + tid;     // 0..5119 16B-chunks
      gload16(xsrc + chunk * 4, (u32*)sB + (chunk & ~63) * 4);
    }
    const u32* wsrc = (const u32*)wt;
    #pragma unroll
    for (int it = 0; it < 4; ++it) {
      int chunk = it * 256 + tid;     // 0..1023
      gload16(wsrc + chunk * 4, (u32*)sA[0] + (chunk & ~63) * 4);
    }
  }
  __syncthreads();   // drains all DMA: sB + sA[0] ready

  for (int octile = 0; octile < 3; ++octile) {
    f32x4 acc[8][4], acc2[8][4];       // rows 2*wave, 2*wave+1
    #pragma unroll
    for (int ms = 0; ms < 8; ++ms)
      #pragma unroll
      for (int ns = 0; ns < 4; ++ns) {
        acc[ms][ns]  = (f32x4){0.f, 0.f, 0.f, 0.f};
        acc2[ms][ns] = (f32x4){0.f, 0.f, 0.f, 0.f};
      }

    #pragma unroll
    for (int tap = 0; tap < 9; ++tap) {
      const int step = octile * 9 + tap;       // octile runtime, tap const
      const int buf = (octile + tap) & 1;      // == step & 1 (9 odd)
      const bool pre = (step < 26);

      // T14 issue-early: next slab's weights -> registers
      u32x4 pf0, pf1, pf2, pf3;
      if (pre) {
        const u16* wnx = wt + (size_t)(step + 1) * WTAP;
        pf0 = *(const u32x4*)&wnx[(0 * 256 + tid) * 8];
        pf1 = *(const u32x4*)&wnx[(1 * 256 + tid) * 8];
        pf2 = *(const u32x4*)&wnx[(2 * 256 + tid) * 8];
        pf3 = *(const u32x4*)&wnx[(3 * 256 + tid) * 8];
      }

      constexpr int dyv[9] = {0,0,0,1,1,1,2,2,2};
      constexpr int dxv[9] = {0,1,2,0,1,2,0,1,2};
      const int dy = dyv[tap], dx = dxv[tap];  // compile-time after unroll
      const u16* sAc = sA[buf];
      __builtin_amdgcn_s_setprio(1);
      #pragma unroll
      for (int kk = 0; kk < 2; ++kk) {
        s16x8 af[8], bf0[4], bf1[4];
        #pragma unroll
        for (int ms = 0; ms < 8; ++ms) {
          int ocl = ms * 16 + lane15;          // full octile
          int po = (kk * 4 + quad) ^ (ocl & 7);
          af[ms] = *(const s16x8*)&sAc[ocl * 64 + po * 8];
        }
        #pragma unroll
        for (int ns = 0; ns < 4; ++ns) {
          int slot = ns * 16 + lane15 + dx;
          int po = (kk * 4 + quad) ^ (slot & 7);
          int row0 = 2 * wave + dy;            // 0..9
          bf0[ns] = *(const s16x8*)&sB[(row0 * 64 + slot) * 64 + po * 8];
          bf1[ns] = *(const s16x8*)&sB[((row0 + 1) * 64 + slot) * 64 + po * 8];
        }
        #pragma unroll
        for (int ms = 0; ms < 8; ++ms)
          #pragma unroll
          for (int ns = 0; ns < 4; ++ns) {
            acc[ms][ns]  = __builtin_amdgcn_mfma_f32_16x16x32_bf16(
                af[ms], bf0[ns], acc[ms][ns], 0, 0, 0);
            acc2[ms][ns] = __builtin_amdgcn_mfma_f32_16x16x32_bf16(
                af[ms], bf1[ns], acc2[ms][ns], 0, 0, 0);
          }
      }
      __builtin_amdgcn_s_setprio(0);

      // T14 write-late: commit prefetched weights to the other buffer.
      if (pre) {
        u16* sAn = sA[buf ^ 1];
        *(u32x4*)&sAn[(0 * 256 + tid) * 8] = pf0;
        *(u32x4*)&sAn[(1 * 256 + tid) * 8] = pf1;
        *(u32x4*)&sAn[(2 * 256 + tid) * 8] = pf2;
        *(u32x4*)&sAn[(3 * 256 + tid) * 8] = pf3;
      }
      __syncthreads();   // publishes sA[buf^1], closes reads of sA[buf]
    }

    // per-octile epilogue: 8 ms x 4 ns x 2 rows x 4 r outputs per lane
    #pragma unroll
    for (int ms = 0; ms < 8; ++ms) {
      int oc0 = octile * 128 + ms * 16 + quad * 4;
      f32x4 sc = *(const f32x4*)&sc1[oc0];
      f32x4 sh = *(const f32x4*)&sh1[oc0];
      float scr[4] = {sc.x, sc.y, sc.z, sc.w};
      float shr[4] = {sh.x, sh.y, sh.z, sh.w};
      #pragma unroll
      for (int ns = 0; ns < 4; ++ns) {
        int xg = ns * 16 + lane15;
        if (xg < Wd) {
          const int ya = y0 + 2 * wave;
          float av[4] = {acc[ms][ns].x, acc[ms][ns].y, acc[ms][ns].z, acc[ms][ns].w};
          float bv[4] = {acc2[ms][ns].x, acc2[ms][ns].y, acc2[ms][ns].z, acc2[ms][ns].w};
          #pragma unroll
          for (int r = 0; r < 4; ++r) {
            float v0 = fsilu(av[r] * scr[r] + shr[r]);
            float v1 = fsilu(bv[r] * scr[r] + shr[r]);
            h[((size_t)(b * HID + oc0 + r) * H + ya) * Wd + xg] = f2b(v0);
            h[((size_t)(b * HID + oc0 + r) * H + ya + 1) * Wd + xg] = f2b(v1);
          }
        }
      }
    }
  }
}

// ---------------------------------------------------------------------------
// K2: depthwise 3x3 + BN2 + SiLU -> d (bf16) + per-(b,c) mean.
// Whole (b,c) plane DMA-staged into LDS once; conv reads from LDS.
// ---------------------------------------------------------------------------
__global__ __launch_bounds__(256) void k_dw(
    const u16* __restrict__ h, const float* __restrict__ wdw,
    const float* __restrict__ g2, const float* __restrict__ b2,
    const float* __restrict__ m2, const float* __restrict__ v2,
    u16* __restrict__ d, float* __restrict__ mean)
{
  __shared__ u32 sdw[1568];           // 56 rows x 28 words = 6272 B
  __shared__ float red[4];
  const int tid = threadIdx.x;
  const int c = blockIdx.x, b = blockIdx.y;
  const u32* hp32 = (const u32*)(h + (size_t)(b * HID + c) * HW);

  // DMA-stage plane: 392 16B chunks (256 + 136)
  gload16(hp32 + tid * 4, sdw + (tid & ~63) * 4);
  if (tid < 136) {
    int chunk = 256 + tid;
    gload16(hp32 + chunk * 4, sdw + (chunk & ~63) * 4);
  }

  f32x2 wv2[9];
  #pragma unroll
  for (int t = 0; t < 9; ++t) {
    float w = wdw[c * 9 + t];
    wv2[t] = (f32x2){w, w};
  }
  const float sc = g2[c] * rsqrtf(v2[c] + EPS);
  const float sh = b2[c] - m2[c] * sc;
  const f32x2 scv = (f32x2){sc, sc}, shv = (f32x2){sh, sh};

  __syncthreads();                    // drains DMA: plane resident in LDS

  float lsum = 0.f;
  if (tid < 224) {
    const int r7 = tid / 28;            // 0..7
    const int wd = tid - r7 * 28;       // 0..27
    const int r0 = r7 * 7;              // first output row
    u32* dp32 = (u32*)(d + (size_t)(b * HID + c) * HW);

    auto loadrow = [&](int rr, f32x2* P) {
      u32 m = 0, c0 = 0, p = 0;
      if (rr >= 0 && rr < 56) {
        const u32* rp = sdw + rr * 28;
        c0 = rp[wd];
        if (wd > 0)  m = rp[wd - 1];
        if (wd < 27) p = rp[wd + 1];
      }
      float f_hm = bfhi(m), f_lc = bflo(c0), f_hc = bfhi(c0), f_lp = bflo(p);
      P[0] = (f32x2){f_hm, f_lc};
      P[1] = (f32x2){f_lc, f_hc};
      P[2] = (f32x2){f_hc, f_lp};
    };

    f32x2 Pa[3], Pb[3], Pc[3];
    loadrow(r0 - 1, Pa);
    loadrow(r0,     Pb);
    f32x2 ls2 = (f32x2){0.f, 0.f};
    #pragma unroll
    for (int i = 0; i < 7; ++i) {
      loadrow(r0 + i + 1, Pc);
      f32x2 s = (f32x2){0.f, 0.f};
      #pragma unroll
      for (int dx = 0; dx < 3; ++dx) s = __builtin_elementwise_fma(Pa[dx], wv2[dx], s);
      #pragma unroll
      for (int dx = 0; dx < 3; ++dx) s = __builtin_elementwise_fma(Pb[dx], wv2[3 + dx], s);
      #pragma unroll
      for (int dx = 0; dx < 3; ++dx) s = __builtin_elementwise_fma(Pc[dx], wv2[6 + dx], s);
      f32x2 t = __builtin_elementwise_fma(s, scv, shv);
      f32x2 val;
      val.x = fsilu(t.x);
      val.y = fsilu(t.y);
      ls2 += val;
      u32 pk;
      asm("v_cvt_pk_bf16_f32 %0, %1, %2" : "=v"(pk) : "v"(val.x), "v"(val.y));
      dp32[(r0 + i) * 28 + wd] = pk;
      #pragma unroll
      for (int q = 0; q < 3; ++q) { Pa[q] = Pb[q]; Pb[q] = Pc[q]; }
    }
    lsum = ls2.x + ls2.y;
  }

  #pragma unroll
  for (int off = 32; off > 0; off >>= 1) lsum += __shfl_down(lsum, off);
  if ((tid & 63) == 0) red[tid >> 6] = lsum;
  __syncthreads();
  if (tid == 0)
    mean[b * HID + c] = (red[0] + red[1] + red[2] + red[3]) * (1.f / 3136.f);
}

// ---------------------------------------------------------------------------
// K3: SE + pointwise-weight fold -> apk[b] (bf16, exact sAw image).
// ---------------------------------------------------------------------------
__global__ __launch_bounds__(256) void k_se_fold(
    const float* __restrict__ mean, const float* __restrict__ w1,
    const float* __restrict__ w2, const float* __restrict__ wpw,
    const float* __restrict__ sc3, u16* __restrict__ apk)
{
  __shared__ float smn[HID];
  __shared__ float sps[16 * 17];
  __shared__ float ss1[16];
  __shared__ float ssf[HID];
  const int b = blockIdx.x, tid = threadIdx.x;
  for (int c = tid; c < HID; c += 256) smn[c] = mean[b * HID + c];
  __syncthreads();
  {
    int r = tid >> 4, j = tid & 15;
    float p = 0.f;
    for (int c = j; c < HID; c += 16) p += smn[c] * w1[r * HID + c];
    sps[r * 17 + j] = p;
  }
  __syncthreads();
  if (tid < 16) {
    float s = 0.f;
    #pragma unroll
    for (int q = 0; q < 16; ++q) s += sps[tid * 17 + q];
    ss1[tid] = fsilu(s);
  }
  __syncthreads();
  for (int c = tid; c < HID; c += 256) {
    float s = 0.f;
    #pragma unroll
    for (int q = 0; q < 16; ++q) s += ss1[q] * w2[c * 16 + q];
    ssf[c] = 1.f / (1.f + __expf(-s));
  }
  __syncthreads();
  u16* ap = apk + (size_t)b * CO * PWP;
  for (int i = tid; i < 6144; i += 256) {
    int e = i * 4, co = e / 384, k = e - co * 384;
    f32x4 wv = *(const f32x4*)&wpw[e];
    f32x4 sf = *(const f32x4*)&ssf[k];
    float s3 = sc3[co];
    u32x2 pk;
    pk.x = (u32)f2b(wv.x * sf.x * s3) | ((u32)f2b(wv.y * sf.y * s3) << 16);
    pk.y = (u32)f2b(wv.z * sf.z * s3) | ((u32)f2b(wv.w * sf.w * s3) << 16);
    *(u32x2*)&ap[co * PWP + k] = pk;
  }
}

// ---------------------------------------------------------------------------
// K4: pointwise MFMA GEMM. Prologue = 13 DMA loads of precomputed apk.
// ---------------------------------------------------------------------------
__global__ __launch_bounds__(256, 2) void k_pw_mfma(
    const u16* __restrict__ d, const u16* __restrict__ apk,
    const float* __restrict__ sh3,
    const float* __restrict__ x, float* __restrict__ out, int b0)
{
  __shared__ u16 sAw[64 * PWP];     // 50,176 B
  __shared__ u32 dtw[4 * 1024];     // 16,384 B
  const int tid = threadIdx.x;
  const int b = blockIdx.y, gb = b0 + b;
  const int p0 = blockIdx.x * 256;
  const int wave = tid >> 6, ln = tid & 63;
  const int lane15 = ln & 15, quad = ln >> 4;

  // stage A' via DMA: 3136 16B chunks
  {
    const u32* ap = (const u32*)(apk + (size_t)b * CO * PWP);
    #pragma unroll
    for (int i = 0; i < 13; ++i) {
      int chunk = i * 256 + tid;
      if (chunk < 3136)
        gload16(ap + chunk * 4, (u32*)sAw + (chunk & ~63) * 4);
    }
  }
  __syncthreads();

  f32x4 acc[4][4];
  #pragma unroll
  for (int ms = 0; ms < 4; ++ms)
    #pragma unroll
    for (int ns = 0; ns < 4; ++ns) acc[ms][ns] = (f32x4){0.f, 0.f, 0.f, 0.f};

  const int cpair8 = ln >> 3;
  const int pxo = (ln & 7) * 8;
  const int swz = ln & 3;
  const int pbase = p0 + wave * 64;
  u32* mydt = &dtw[wave * 1024];
  const bool ld_ok = (pbase + pxo + 8 <= HW);
  const u16* dbase = d + (size_t)b * HID * HW + pbase + pxo;

  u32x4 pr0[2], pr1[2];
  #pragma unroll
  for (int ci = 0; ci < 2; ++ci) {
    pr0[ci] = (u32x4){0,0,0,0}; pr1[ci] = (u32x4){0,0,0,0};
    if (ld_ok) {
      int c = 2 * (ci * 8 + cpair8);
      const u16* dpp = dbase + (size_t)c * HW;
      pr0[ci] = *(const u32x4*)dpp;
      pr1[ci] = *(const u32x4*)(dpp + HW);
    }
  }

  for (int ks = 0; ks < 12; ++ks) {
    #pragma unroll
    for (int ci = 0; ci < 2; ++ci) {
      int k4 = ci * 2 + (cpair8 >> 2);
      u32* w0 = &mydt[pxo * 16 + ((k4 ^ swz) << 2) + (cpair8 & 3)];
      u32x4 r0 = pr0[ci], r1 = pr1[ci];
      w0[0 * 16] = (r0.x & 0xffffu) | (r1.x << 16);
      w0[1 * 16] = (r0.x >> 16)     | (r1.x & 0xffff0000u);
      w0[2 * 16] = (r0.y & 0xffffu) | (r1.y << 16);
      w0[3 * 16] = (r0.y >> 16)     | (r1.y & 0xffff0000u);
      w0[4 * 16] = (r0.z & 0xffffu) | (r1.z << 16);
      w0[5 * 16] = (r0.z >> 16)     | (r1.z & 0xffff0000u);
      w0[6 * 16] = (r0.w & 0xffffu) | (r1.w << 16);
      w0[7 * 16] = (r0.w >> 16)     | (r1.w & 0xffff0000u);
    }
    if (ks < 11) {
      #pragma unroll
      for (int ci = 0; ci < 2; ++ci) {
        if (ld_ok) {
          int c = (ks + 1) * 32 + 2 * (ci * 8 + cpair8);
          const u16* dpp = dbase + (size_t)c * HW;
          pr0[ci] = *(const u32x4*)dpp;
          pr1[ci] = *(const u32x4*)(dpp + HW);
        }
      }
    }
    const int k0 = ks * 32;
    s16x8 af[4], bf[4];
    #pragma unroll
    for (int ms = 0; ms < 4; ++ms) {
      int ocl = ms * 16 + lane15;
      af[ms] = *(const s16x8*)&sAw[ocl * PWP + k0 + quad * 8];
    }
    #pragma unroll
    for (int ns = 0; ns < 4; ++ns) {
      int pxl = ns * 16 + lane15;
      int p4 = quad ^ ((pxl >> 3) & 3);
      bf[ns] = *(const s16x8*)((const u16*)mydt + pxl * 32 + p4 * 8);
    }
    #pragma unroll
    for (int ms = 0; ms < 4; ++ms)
      #pragma unroll
      for (int ns = 0; ns < 4; ++ns)
        acc[ms][ns] = __builtin_amdgcn_mfma_f32_16x16x32_bf16(
            af[ms], bf[ns], acc[ms][ns], 0, 0, 0);
  }

  #pragma unroll
  for (int ns = 0; ns < 4; ++ns) {
    int p = pbase + ns * 16 + lane15;
    if (p < HW) {
      #pragma unroll
      for (int ms = 0; ms < 4; ++ms) {
        int co0 = ms * 16 + quad * 4;
        float av[4] = {acc[ms][ns].x, acc[ms][ns].y, acc[ms][ns].z, acc[ms][ns].w};
        #pragma unroll
        for (int r = 0; r < 4; ++r) {
          size_t idx = (size_t)(gb * CO + co0 + r) * HW + p;
          out[idx] = av[r] + sh3[co0 + r] + x[idx];
        }
      }
    }
  }
}

// ---------------------------------------------------------------------------
extern "C" void kernel_launch(void* const* d_in, const int* in_sizes, int n_in,
                              void* d_out, int out_size, void* d_ws, size_t ws_size,
                              hipStream_t stream)
{
  (void)in_sizes; (void)n_in; (void)out_size;
  const float* x     = (const float*)d_in[0];
  const float* w_exp = (const float*)d_in[1];
  const float* g1 = (const float*)d_in[2];
  const float* b1 = (const float*)d_in[3];
  const float* m1 = (const float*)d_in[4];
  const float* v1 = (const float*)d_in[5];
  const float* w_dw = (const float*)d_in[6];
  const float* g2 = (const float*)d_in[7];
  const float* b2 = (const float*)d_in[8];
  const float* m2 = (const float*)d_in[9];
  const float* v2 = (const float*)d_in[10];
  const float* w_se1 = (const float*)d_in[11];
  const float* w_se2 = (const float*)d_in[12];
  const float* w_pw  = (const float*)d_in[13];
  const float* g3 = (const float*)d_in[14];
  const float* b3 = (const float*)d_in[15];
  const float* m3 = (const float*)d_in[16];
  const float* v3 = (const float*)d_in[17];

  // per-batch: h + dd (bf16) + mean + xt + apk
  const size_t perB = (size_t)HID * HW * 2 * 2 + HID * 4
                    + (size_t)58 * XTROW * 2 + (size_t)CO * PWP * 2;
  const size_t fixed = 221184 * 2 + HID * 8 + CO * 8;
  int bc = Bn;
  while (bc > 1 && fixed + (size_t)bc * perB > ws_size) bc >>= 1;

  u16* wt = (u16*)d_ws;
  float* sc1 = (float*)(wt + 221184);
  float* sh1 = sc1 + HID;
  float* sc3 = sh1 + HID;
  float* sh3 = sc3 + CO;
  u16* h  = (u16*)(sh3 + CO);
  u16* dd = h + (size_t)bc * HID * HW;
  float* mean = (float*)(dd + (size_t)bc * HID * HW);
  u16* xt = (u16*)(mean + (size_t)bc * HID);
  u16* apk = xt + (size_t)bc * 58 * XTROW;

  k_prep_wbn<<<865, 256, 0, stream>>>(w_exp, g1, b1, m1, v1, g3, b3, m3, v3,
                                      wt, sc1, sh1, sc3, sh3);

  for (int b0 = 0; b0 < Bn; b0 += bc) {
    k_prep_x<<<dim3(58, bc), 256, 0, stream>>>(x, xt, b0);
    k_expand_mfma<<<dim3(7, bc), 256, 0, stream>>>(xt, wt, sc1, sh1, h, b0);
    k_dw<<<dim3(HID, bc), 256, 0, stream>>>(h, w_dw, g2, b2, m2, v2, dd, mean);
    k_se_fold<<<bc, 256, 0, stream>>>(mean, w_se1, w_se2, w_pw, sc3, apk);
    k_pw_mfma<<<dim3(13, bc), 256, 0, stream>>>(dd, apk, sh3,
                                                x, (float*)d_out, b0);
  }
}

// Round 14
// 242.837 us; speedup vs baseline: 1.1315x; 1.1315x over previous
//
#include <hip/hip_runtime.h>

typedef unsigned short u16;
typedef unsigned int u32;
typedef __attribute__((ext_vector_type(2))) u32 u32x2;
typedef __attribute__((ext_vector_type(4))) u32 u32x4;
typedef __attribute__((ext_vector_type(2))) float f32x2;
typedef __attribute__((ext_vector_type(4))) float f32x4;
typedef __attribute__((ext_vector_type(8))) short s16x8;

#define DEV __device__ __forceinline__

DEV float bflo(u32 u){ union{u32 i; float f;} c; c.i = u << 16; return c.f; }
DEV float bfhi(u32 u){ union{u32 i; float f;} c; c.i = u & 0xffff0000u; return c.f; }
DEV u16 f2b(float f){
  union{float f; u32 u;} c; c.f = f;
  u32 u = c.u;
  u32 r = (u + 0x7fffu + ((u >> 16) & 1u)) >> 16;
  return (u16)r;
}
DEV float fsilu(float v){ return v / (1.f + __expf(-v)); }

// async global->LDS DMA, 16B per lane; LDS dest = wave-uniform base + lane*16
typedef const __attribute__((address_space(1))) u32 gu32;
typedef __attribute__((address_space(3))) u32 lu32;
DEV void gload16(const u32* g, u32* l) {
  __builtin_amdgcn_global_load_lds((gu32*)g, (lu32*)l, 16, 0, 0);
}

constexpr int Bn = 32, Cin = 64, H = 56, Wd = 56, HID = 384, CO = 64;
constexpr int HW = H * Wd;            // 3136
constexpr float EPS = 1e-5f;

constexpr int WTAP = 128 * 64;
constexpr int WOCT = 9 * WTAP;
constexpr int XTROW = 64 * 64;        // xt/sB row = 64 slots x 64 ic (8KB)
constexpr int PWP = 392;              // sAw row pitch (u16) — bank-safe

// ---------------------------------------------------------------------------
// P1: pack expand weights -> wt (swizzled) + BN1/BN3 scale-shift (block 864).
// ---------------------------------------------------------------------------
__global__ __launch_bounds__(256) void k_prep_wbn(
    const float* __restrict__ w,
    const float* __restrict__ g1, const float* __restrict__ b1,
    const float* __restrict__ m1, const float* __restrict__ v1,
    const float* __restrict__ g3, const float* __restrict__ b3,
    const float* __restrict__ m3, const float* __restrict__ v3,
    u16* __restrict__ wt,
    float* __restrict__ sc1, float* __restrict__ sh1,
    float* __restrict__ sc3, float* __restrict__ sh3)
{
  const int blk = blockIdx.x;
  if (blk < 864) {
    int t = blk * 256 + threadIdx.x;
    int octile = t / WOCT, r = t - octile * WOCT;
    int tap = r / WTAP, r2 = r - tap * WTAP;
    int ocl = r2 >> 6, col = r2 & 63;
    int physo = col >> 3, j = col & 7;
    int olog = physo ^ (ocl & 7);
    int ic = olog * 8 + j;
    int oc = octile * 128 + ocl;
    wt[t] = f2b(w[(oc * Cin + ic) * 9 + tap]);
  } else {
    for (int t = threadIdx.x; t < HID; t += 256) {
      float sc = g1[t] * rsqrtf(v1[t] + EPS);
      sc1[t] = sc;
      sh1[t] = b1[t] - m1[t] * sc;
    }
    if (threadIdx.x < CO) {
      int t = threadIdx.x;
      float sc = g3[t] * rsqrtf(v3[t] + EPS);
      sc3[t] = sc;
      sh3[t] = b3[t] - m3[t] * sc;
    }
  }
}

// ---------------------------------------------------------------------------
// P2: x -> xt bf16 swizzled [b][row 58][slot 64][ic 64].
// row = y+1; rows 0 and 57 zero halo; slots 0 and 57..63 zero.
// ---------------------------------------------------------------------------
__global__ __launch_bounds__(256) void k_prep_x(
    const float* __restrict__ x, u16* __restrict__ xt, int b0)
{
  const int row = blockIdx.x;         // 0..57
  const int b = blockIdx.y, gb = b0 + b;
  const int tid = threadIdx.x;
  u16* dst = xt + ((size_t)b * 58 + row) * XTROW;
  if (row == 0 || row == 57) {
    for (int i = tid; i < 2048; i += 256) ((u32*)dst)[i] = 0;
    return;
  }
  const int y = row - 1;
  __shared__ u16 sx[64 * 58];         // [ic][px], pitch 58
  {
    const int ic = tid >> 2, seg = tid & 3;
    const float* xp = x + ((size_t)(gb * Cin + ic) * H + y) * Wd + seg * 14;
    #pragma unroll
    for (int t = 0; t < 14; ++t) sx[ic * 58 + seg * 14 + t] = f2b(xp[t]);
  }
  __syncthreads();
  #pragma unroll
  for (int it = 0; it < 16; ++it) {
    const int slot = it * 4 + (tid >> 6);   // 0..63
    const int j = tid & 63;
    u16 v = 0;
    if (slot >= 1 && slot <= 56) {
      int ic = (((j >> 3) ^ (slot & 7)) << 3) | (j & 7);
      v = sx[ic * 58 + (slot - 1)];
    }
    dst[slot * 64 + j] = v;           // 128B contiguous per wave-slot
  }
}

// ---------------------------------------------------------------------------
// K1 (r23 = r21): expand conv MFMA shift-GEMM — fat-wave, 1 row/wave.
// Block = y-QUAD, 4 waves = 4 rows; wave = full octile 128oc x 64px
// (acc[8][4] = 128 VGPR). 0.375 LDS-reads/MFMA — the geometric floor at
// <=128 acc regs (r22's 2-row 0.28 tile needs 256 regs -> 1 wave/SIMD,
// regressed 70->96us). Grid 14x32 = 448 blocks @ 2/CU, zero tail.
// ---------------------------------------------------------------------------
__global__ __launch_bounds__(256, 2) void k_expand_mfma(
    const u16* __restrict__ xt, const u16* __restrict__ wt,
    const float* __restrict__ sc1, const float* __restrict__ sh1,
    u16* __restrict__ h, int b0)
{
  (void)b0;
  __shared__ u16 sB[6 * XTROW];      // 49,152 B : xt rows y0..y0+5
  __shared__ u16 sA[2][WTAP];        // 32,768 B
  const int tid = threadIdx.x;
  const int yq = blockIdx.x, b = blockIdx.y;
  const int y0 = yq * 4;
  const int wave = tid >> 6, ln = tid & 63;
  const int lane15 = ln & 15, quad = ln >> 4;

  // prologue staging: sB (6 xt rows = input y0-1..y0+4) + sA[0], all DMA
  {
    const u32* xsrc = (const u32*)(xt + ((size_t)b * 58 + y0) * XTROW);
    #pragma unroll
    for (int it = 0; it < 12; ++it) {
      int chunk = it * 256 + tid;     // 0..3071 16B-chunks
      gload16(xsrc + chunk * 4, (u32*)sB + (chunk & ~63) * 4);
    }
    const u32* wsrc = (const u32*)wt;
    #pragma unroll
    for (int it = 0; it < 4; ++it) {
      int chunk = it * 256 + tid;     // 0..1023
      gload16(wsrc + chunk * 4, (u32*)sA[0] + (chunk & ~63) * 4);
    }
  }
  __syncthreads();   // drains all DMA: sB + sA[0] ready

  const int y = y0 + wave;            // this wave's output row

  for (int octile = 0; octile < 3; ++octile) {
    f32x4 acc[8][4];
    #pragma unroll
    for (int ms = 0; ms < 8; ++ms)
      #pragma unroll
      for (int ns = 0; ns < 4; ++ns) acc[ms][ns] = (f32x4){0.f, 0.f, 0.f, 0.f};

    #pragma unroll
    for (int tap = 0; tap < 9; ++tap) {
      const int step = octile * 9 + tap;       // octile runtime, tap const
      const int buf = (octile + tap) & 1;      // == step & 1 (9 odd)
      const bool pre = (step < 26);

      // T14 issue-early: next slab's weights -> registers
      u32x4 pf0, pf1, pf2, pf3;
      if (pre) {
        const u16* wnx = wt + (size_t)(step + 1) * WTAP;
        pf0 = *(const u32x4*)&wnx[(0 * 256 + tid) * 8];
        pf1 = *(const u32x4*)&wnx[(1 * 256 + tid) * 8];
        pf2 = *(const u32x4*)&wnx[(2 * 256 + tid) * 8];
        pf3 = *(const u32x4*)&wnx[(3 * 256 + tid) * 8];
      }

      constexpr int dyv[9] = {0,0,0,1,1,1,2,2,2};
      constexpr int dxv[9] = {0,1,2,0,1,2,0,1,2};
      const int dy = dyv[tap], dx = dxv[tap];  // compile-time after unroll
      const u16* sAc = sA[buf];
      __builtin_amdgcn_s_setprio(1);
      #pragma unroll
      for (int kk = 0; kk < 2; ++kk) {
        s16x8 bf[4];
        #pragma unroll
        for (int ns = 0; ns < 4; ++ns) {
          int row = wave + dy;                 // 0..5
          int slot = ns * 16 + lane15 + dx;
          int po = (kk * 4 + quad) ^ (slot & 7);
          bf[ns] = *(const s16x8*)&sB[(row * 64 + slot) * 64 + po * 8];
        }
        #pragma unroll
        for (int ms = 0; ms < 8; ++ms) {
          int ocl = ms * 16 + lane15;          // 0..127: full octile
          int po = (kk * 4 + quad) ^ (ocl & 7);
          s16x8 af = *(const s16x8*)&sAc[ocl * 64 + po * 8];
          #pragma unroll
          for (int ns = 0; ns < 4; ++ns)
            acc[ms][ns] = __builtin_amdgcn_mfma_f32_16x16x32_bf16(
                af, bf[ns], acc[ms][ns], 0, 0, 0);
        }
      }
      __builtin_amdgcn_s_setprio(0);

      // T14 write-late: commit prefetched weights to the other buffer.
      if (pre) {
        u16* sAn = sA[buf ^ 1];
        *(u32x4*)&sAn[(0 * 256 + tid) * 8] = pf0;
        *(u32x4*)&sAn[(1 * 256 + tid) * 8] = pf1;
        *(u32x4*)&sAn[(2 * 256 + tid) * 8] = pf2;
        *(u32x4*)&sAn[(3 * 256 + tid) * 8] = pf3;
      }
      __syncthreads();   // publishes sA[buf^1], closes reads of sA[buf]
    }

    // per-octile epilogue: 8 ms x 4 ns x 4 r outputs per wave
    #pragma unroll
    for (int ms = 0; ms < 8; ++ms) {
      int oc0 = octile * 128 + ms * 16 + quad * 4;
      f32x4 sc = *(const f32x4*)&sc1[oc0];
      f32x4 sh = *(const f32x4*)&sh1[oc0];
      float scr[4] = {sc.x, sc.y, sc.z, sc.w};
      float shr[4] = {sh.x, sh.y, sh.z, sh.w};
      #pragma unroll
      for (int ns = 0; ns < 4; ++ns) {
        int xg = ns * 16 + lane15;
        if (xg < Wd) {
          float av[4] = {acc[ms][ns].x, acc[ms][ns].y, acc[ms][ns].z, acc[ms][ns].w};
          #pragma unroll
          for (int r = 0; r < 4; ++r) {
            float val = fsilu(av[r] * scr[r] + shr[r]);
            h[((size_t)(b * HID + oc0 + r) * H + y) * Wd + xg] = f2b(val);
          }
        }
      }
    }
  }
}

// ---------------------------------------------------------------------------
// K2: depthwise 3x3 + BN2 + SiLU -> d (bf16) + per-(b,c) mean.
// Whole (b,c) plane DMA-staged into LDS once; conv reads from LDS.
// ---------------------------------------------------------------------------
__global__ __launch_bounds__(256) void k_dw(
    const u16* __restrict__ h, const float* __restrict__ wdw,
    const float* __restrict__ g2, const float* __restrict__ b2,
    const float* __restrict__ m2, const float* __restrict__ v2,
    u16* __restrict__ d, float* __restrict__ mean)
{
  __shared__ u32 sdw[1568];           // 56 rows x 28 words = 6272 B
  __shared__ float red[4];
  const int tid = threadIdx.x;
  const int c = blockIdx.x, b = blockIdx.y;
  const u32* hp32 = (const u32*)(h + (size_t)(b * HID + c) * HW);

  // DMA-stage plane: 392 16B chunks (256 + 136)
  gload16(hp32 + tid * 4, sdw + (tid & ~63) * 4);
  if (tid < 136) {
    int chunk = 256 + tid;
    gload16(hp32 + chunk * 4, sdw + (chunk & ~63) * 4);
  }

  f32x2 wv2[9];
  #pragma unroll
  for (int t = 0; t < 9; ++t) {
    float w = wdw[c * 9 + t];
    wv2[t] = (f32x2){w, w};
  }
  const float sc = g2[c] * rsqrtf(v2[c] + EPS);
  const float sh = b2[c] - m2[c] * sc;
  const f32x2 scv = (f32x2){sc, sc}, shv = (f32x2){sh, sh};

  __syncthreads();                    // drains DMA: plane resident in LDS

  float lsum = 0.f;
  if (tid < 224) {
    const int r7 = tid / 28;            // 0..7
    const int wd = tid - r7 * 28;       // 0..27
    const int r0 = r7 * 7;              // first output row
    u32* dp32 = (u32*)(d + (size_t)(b * HID + c) * HW);

    auto loadrow = [&](int rr, f32x2* P) {
      u32 m = 0, c0 = 0, p = 0;
      if (rr >= 0 && rr < 56) {
        const u32* rp = sdw + rr * 28;
        c0 = rp[wd];
        if (wd > 0)  m = rp[wd - 1];
        if (wd < 27) p = rp[wd + 1];
      }
      float f_hm = bfhi(m), f_lc = bflo(c0), f_hc = bfhi(c0), f_lp = bflo(p);
      P[0] = (f32x2){f_hm, f_lc};
      P[1] = (f32x2){f_lc, f_hc};
      P[2] = (f32x2){f_hc, f_lp};
    };

    f32x2 Pa[3], Pb[3], Pc[3];
    loadrow(r0 - 1, Pa);
    loadrow(r0,     Pb);
    f32x2 ls2 = (f32x2){0.f, 0.f};
    #pragma unroll
    for (int i = 0; i < 7; ++i) {
      loadrow(r0 + i + 1, Pc);
      f32x2 s = (f32x2){0.f, 0.f};
      #pragma unroll
      for (int dx = 0; dx < 3; ++dx) s = __builtin_elementwise_fma(Pa[dx], wv2[dx], s);
      #pragma unroll
      for (int dx = 0; dx < 3; ++dx) s = __builtin_elementwise_fma(Pb[dx], wv2[3 + dx], s);
      #pragma unroll
      for (int dx = 0; dx < 3; ++dx) s = __builtin_elementwise_fma(Pc[dx], wv2[6 + dx], s);
      f32x2 t = __builtin_elementwise_fma(s, scv, shv);
      f32x2 val;
      val.x = fsilu(t.x);
      val.y = fsilu(t.y);
      ls2 += val;
      u32 pk;
      asm("v_cvt_pk_bf16_f32 %0, %1, %2" : "=v"(pk) : "v"(val.x), "v"(val.y));
      dp32[(r0 + i) * 28 + wd] = pk;
      #pragma unroll
      for (int q = 0; q < 3; ++q) { Pa[q] = Pb[q]; Pb[q] = Pc[q]; }
    }
    lsum = ls2.x + ls2.y;
  }

  #pragma unroll
  for (int off = 32; off > 0; off >>= 1) lsum += __shfl_down(lsum, off);
  if ((tid & 63) == 0) red[tid >> 6] = lsum;
  __syncthreads();
  if (tid == 0)
    mean[b * HID + c] = (red[0] + red[1] + red[2] + red[3]) * (1.f / 3136.f);
}

// ---------------------------------------------------------------------------
// K3 (r23): SE + pointwise-weight fold -> apk[b]. Grid (2, bc): both halves
// recompute the tiny SE; each folds half of apk -> half the serialization
// bubble gating k_pw (was 32 blocks on 256 CUs).
// ---------------------------------------------------------------------------
__global__ __launch_bounds__(256) void k_se_fold(
    const float* __restrict__ mean, const float* __restrict__ w1,
    const float* __restrict__ w2, const float* __restrict__ wpw,
    const float* __restrict__ sc3, u16* __restrict__ apk)
{
  __shared__ float smn[HID];
  __shared__ float sps[16 * 17];
  __shared__ float ss1[16];
  __shared__ float ssf[HID];
  const int half = blockIdx.x, b = blockIdx.y, tid = threadIdx.x;
  for (int c = tid; c < HID; c += 256) smn[c] = mean[b * HID + c];
  __syncthreads();
  {
    int r = tid >> 4, j = tid & 15;
    float p = 0.f;
    for (int c = j; c < HID; c += 16) p += smn[c] * w1[r * HID + c];
    sps[r * 17 + j] = p;
  }
  __syncthreads();
  if (tid < 16) {
    float s = 0.f;
    #pragma unroll
    for (int q = 0; q < 16; ++q) s += sps[tid * 17 + q];
    ss1[tid] = fsilu(s);
  }
  __syncthreads();
  for (int c = tid; c < HID; c += 256) {
    float s = 0.f;
    #pragma unroll
    for (int q = 0; q < 16; ++q) s += ss1[q] * w2[c * 16 + q];
    ssf[c] = 1.f / (1.f + __expf(-s));
  }
  __syncthreads();
  u16* ap = apk + (size_t)b * CO * PWP;
  for (int i = half * 3072 + tid; i < (half + 1) * 3072; i += 256) {
    int e = i * 4, co = e / 384, k = e - co * 384;
    f32x4 wv = *(const f32x4*)&wpw[e];
    f32x4 sf = *(const f32x4*)&ssf[k];
    float s3 = sc3[co];
    u32x2 pk;
    pk.x = (u32)f2b(wv.x * sf.x * s3) | ((u32)f2b(wv.y * sf.y * s3) << 16);
    pk.y = (u32)f2b(wv.z * sf.z * s3) | ((u32)f2b(wv.w * sf.w * s3) << 16);
    *(u32x2*)&ap[co * PWP + k] = pk;
  }
}

// ---------------------------------------------------------------------------
// K4 (r23): pointwise MFMA GEMM + setprio around read+MFMA cluster (T5:
// barrier-free loop, waves role-diverse -> attention-like case).
// ---------------------------------------------------------------------------
__global__ __launch_bounds__(256, 2) void k_pw_mfma(
    const u16* __restrict__ d, const u16* __restrict__ apk,
    const float* __restrict__ sh3,
    const float* __restrict__ x, float* __restrict__ out, int b0)
{
  __shared__ u16 sAw[64 * PWP];     // 50,176 B
  __shared__ u32 dtw[4 * 1024];     // 16,384 B
  const int tid = threadIdx.x;
  const int b = blockIdx.y, gb = b0 + b;
  const int p0 = blockIdx.x * 256;
  const int wave = tid >> 6, ln = tid & 63;
  const int lane15 = ln & 15, quad = ln >> 4;

  // stage A' via DMA: 3136 16B chunks
  {
    const u32* ap = (const u32*)(apk + (size_t)b * CO * PWP);
    #pragma unroll
    for (int i = 0; i < 13; ++i) {
      int chunk = i * 256 + tid;
      if (chunk < 3136)
        gload16(ap + chunk * 4, (u32*)sAw + (chunk & ~63) * 4);
    }
  }
  __syncthreads();

  f32x4 acc[4][4];
  #pragma unroll
  for (int ms = 0; ms < 4; ++ms)
    #pragma unroll
    for (int ns = 0; ns < 4; ++ns) acc[ms][ns] = (f32x4){0.f, 0.f, 0.f, 0.f};

  const int cpair8 = ln >> 3;
  const int pxo = (ln & 7) * 8;
  const int swz = ln & 3;
  const int pbase = p0 + wave * 64;
  u32* mydt = &dtw[wave * 1024];
  const bool ld_ok = (pbase + pxo + 8 <= HW);
  const u16* dbase = d + (size_t)b * HID * HW + pbase + pxo;

  u32x4 pr0[2], pr1[2];
  #pragma unroll
  for (int ci = 0; ci < 2; ++ci) {
    pr0[ci] = (u32x4){0,0,0,0}; pr1[ci] = (u32x4){0,0,0,0};
    if (ld_ok) {
      int c = 2 * (ci * 8 + cpair8);
      const u16* dpp = dbase + (size_t)c * HW;
      pr0[ci] = *(const u32x4*)dpp;
      pr1[ci] = *(const u32x4*)(dpp + HW);
    }
  }

  for (int ks = 0; ks < 12; ++ks) {
    #pragma unroll
    for (int ci = 0; ci < 2; ++ci) {
      int k4 = ci * 2 + (cpair8 >> 2);
      u32* w0 = &mydt[pxo * 16 + ((k4 ^ swz) << 2) + (cpair8 & 3)];
      u32x4 r0 = pr0[ci], r1 = pr1[ci];
      w0[0 * 16] = (r0.x & 0xffffu) | (r1.x << 16);
      w0[1 * 16] = (r0.x >> 16)     | (r1.x & 0xffff0000u);
      w0[2 * 16] = (r0.y & 0xffffu) | (r1.y << 16);
      w0[3 * 16] = (r0.y >> 16)     | (r1.y & 0xffff0000u);
      w0[4 * 16] = (r0.z & 0xffffu) | (r1.z << 16);
      w0[5 * 16] = (r0.z >> 16)     | (r1.z & 0xffff0000u);
      w0[6 * 16] = (r0.w & 0xffffu) | (r1.w << 16);
      w0[7 * 16] = (r0.w >> 16)     | (r1.w & 0xffff0000u);
    }
    if (ks < 11) {
      #pragma unroll
      for (int ci = 0; ci < 2; ++ci) {
        if (ld_ok) {
          int c = (ks + 1) * 32 + 2 * (ci * 8 + cpair8);
          const u16* dpp = dbase + (size_t)c * HW;
          pr0[ci] = *(const u32x4*)dpp;
          pr1[ci] = *(const u32x4*)(dpp + HW);
        }
      }
    }
    const int k0 = ks * 32;
    __builtin_amdgcn_s_setprio(1);
    s16x8 af[4], bf[4];
    #pragma unroll
    for (int ms = 0; ms < 4; ++ms) {
      int ocl = ms * 16 + lane15;
      af[ms] = *(const s16x8*)&sAw[ocl * PWP + k0 + quad * 8];
    }
    #pragma unroll
    for (int ns = 0; ns < 4; ++ns) {
      int pxl = ns * 16 + lane15;
      int p4 = quad ^ ((pxl >> 3) & 3);
      bf[ns] = *(const s16x8*)((const u16*)mydt + pxl * 32 + p4 * 8);
    }
    #pragma unroll
    for (int ms = 0; ms < 4; ++ms)
      #pragma unroll
      for (int ns = 0; ns < 4; ++ns)
        acc[ms][ns] = __builtin_amdgcn_mfma_f32_16x16x32_bf16(
            af[ms], bf[ns], acc[ms][ns], 0, 0, 0);
    __builtin_amdgcn_s_setprio(0);
  }

  #pragma unroll
  for (int ns = 0; ns < 4; ++ns) {
    int p = pbase + ns * 16 + lane15;
    if (p < HW) {
      #pragma unroll
      for (int ms = 0; ms < 4; ++ms) {
        int co0 = ms * 16 + quad * 4;
        float av[4] = {acc[ms][ns].x, acc[ms][ns].y, acc[ms][ns].z, acc[ms][ns].w};
        #pragma unroll
        for (int r = 0; r < 4; ++r) {
          size_t idx = (size_t)(gb * CO + co0 + r) * HW + p;
          out[idx] = av[r] + sh3[co0 + r] + x[idx];
        }
      }
    }
  }
}

// ---------------------------------------------------------------------------
extern "C" void kernel_launch(void* const* d_in, const int* in_sizes, int n_in,
                              void* d_out, int out_size, void* d_ws, size_t ws_size,
                              hipStream_t stream)
{
  (void)in_sizes; (void)n_in; (void)out_size;
  const float* x     = (const float*)d_in[0];
  const float* w_exp = (const float*)d_in[1];
  const float* g1 = (const float*)d_in[2];
  const float* b1 = (const float*)d_in[3];
  const float* m1 = (const float*)d_in[4];
  const float* v1 = (const float*)d_in[5];
  const float* w_dw = (const float*)d_in[6];
  const float* g2 = (const float*)d_in[7];
  const float* b2 = (const float*)d_in[8];
  const float* m2 = (const float*)d_in[9];
  const float* v2 = (const float*)d_in[10];
  const float* w_se1 = (const float*)d_in[11];
  const float* w_se2 = (const float*)d_in[12];
  const float* w_pw  = (const float*)d_in[13];
  const float* g3 = (const float*)d_in[14];
  const float* b3 = (const float*)d_in[15];
  const float* m3 = (const float*)d_in[16];
  const float* v3 = (const float*)d_in[17];

  // per-batch: h + dd (bf16) + mean + xt + apk
  const size_t perB = (size_t)HID * HW * 2 * 2 + HID * 4
                    + (size_t)58 * XTROW * 2 + (size_t)CO * PWP * 2;
  const size_t fixed = 221184 * 2 + HID * 8 + CO * 8;
  int bc = Bn;
  while (bc > 1 && fixed + (size_t)bc * perB > ws_size) bc >>= 1;

  u16* wt = (u16*)d_ws;
  float* sc1 = (float*)(wt + 221184);
  float* sh1 = sc1 + HID;
  float* sc3 = sh1 + HID;
  float* sh3 = sc3 + CO;
  u16* h  = (u16*)(sh3 + CO);
  u16* dd = h + (size_t)bc * HID * HW;
  float* mean = (float*)(dd + (size_t)bc * HID * HW);
  u16* xt = (u16*)(mean + (size_t)bc * HID);
  u16* apk = xt + (size_t)bc * 58 * XTROW;

  k_prep_wbn<<<865, 256, 0, stream>>>(w_exp, g1, b1, m1, v1, g3, b3, m3, v3,
                                      wt, sc1, sh1, sc3, sh3);

  for (int b0 = 0; b0 < Bn; b0 += bc) {
    k_prep_x<<<dim3(58, bc), 256, 0, stream>>>(x, xt, b0);
    k_expand_mfma<<<dim3(14, bc), 256, 0, stream>>>(xt, wt, sc1, sh1, h, b0);
    k_dw<<<dim3(HID, bc), 256, 0, stream>>>(h, w_dw, g2, b2, m2, v2, dd, mean);
    k_se_fold<<<dim3(2, bc), 256, 0, stream>>>(mean, w_se1, w_se2, w_pw, sc3, apk);
    k_pw_mfma<<<dim3(13, bc), 256, 0, stream>>>(dd, apk, sh3,
                                                x, (float*)d_out, b0);
  }
}

// Round 16
// 223.653 us; speedup vs baseline: 1.2285x; 1.0858x over previous
//
#include <hip/hip_runtime.h>

typedef unsigned short u16;
typedef unsigned int u32;
typedef __attribute__((ext_vector_type(2))) u32 u32x2;
typedef __attribute__((ext_vector_type(4))) u32 u32x4;
typedef __attribute__((ext_vector_type(2))) float f32x2;
typedef __attribute__((ext_vector_type(4))) float f32x4;
typedef __attribute__((ext_vector_type(8))) short s16x8;

#define DEV __device__ __forceinline__

DEV float bflo(u32 u){ union{u32 i; float f;} c; c.i = u << 16; return c.f; }
DEV float bfhi(u32 u){ union{u32 i; float f;} c; c.i = u & 0xffff0000u; return c.f; }
DEV u16 f2b(float f){
  union{float f; u32 u;} c; c.f = f;
  u32 u = c.u;
  u32 r = (u + 0x7fffu + ((u >> 16) & 1u)) >> 16;
  return (u16)r;
}
// RNE bf16 via HW packed convert — bit-identical to f2b, 1 VALU op.
DEV u16 f2bq(float f){
  u32 pk;
  asm("v_cvt_pk_bf16_f32 %0, %1, %2" : "=v"(pk) : "v"(f), "v"(f));
  return (u16)pk;
}
DEV u32 pk2b(float lo, float hi){
  u32 pk;
  asm("v_cvt_pk_bf16_f32 %0, %1, %2" : "=v"(pk) : "v"(lo), "v"(hi));
  return pk;
}
// fast silu/sigmoid: v_rcp_f32 (<=1ulp) instead of IEEE divide sequence.
DEV float frcp(float x){ return __builtin_amdgcn_rcpf(x); }
DEV float fsilu(float v){ return v * frcp(1.f + __expf(-v)); }

// async global->LDS DMA, 16B per lane; LDS dest = wave-uniform base + lane*16
typedef const __attribute__((address_space(1))) u32 gu32;
typedef __attribute__((address_space(3))) u32 lu32;
DEV void gload16(const u32* g, u32* l) {
  __builtin_amdgcn_global_load_lds((gu32*)g, (lu32*)l, 16, 0, 0);
}

constexpr int Bn = 32, Cin = 64, H = 56, Wd = 56, HID = 384, CO = 64;
constexpr int HW = H * Wd;            // 3136
constexpr float EPS = 1e-5f;

constexpr int WTAP = 128 * 64;
constexpr int WOCT = 9 * WTAP;
constexpr int XTROW = 64 * 64;        // xt/sB row = 64 slots x 64 ic (8KB)
constexpr int PWP = 392;              // sAw row pitch (u16) — bank-safe

// ---------------------------------------------------------------------------
// P1: pack expand weights -> wt (swizzled) + BN1/BN3 scale-shift (block 864).
// ---------------------------------------------------------------------------
__global__ __launch_bounds__(256) void k_prep_wbn(
    const float* __restrict__ w,
    const float* __restrict__ g1, const float* __restrict__ b1,
    const float* __restrict__ m1, const float* __restrict__ v1,
    const float* __restrict__ g3, const float* __restrict__ b3,
    const float* __restrict__ m3, const float* __restrict__ v3,
    u16* __restrict__ wt,
    float* __restrict__ sc1, float* __restrict__ sh1,
    float* __restrict__ sc3, float* __restrict__ sh3)
{
  const int blk = blockIdx.x;
  if (blk < 864) {
    int t = blk * 256 + threadIdx.x;
    int octile = t / WOCT, r = t - octile * WOCT;
    int tap = r / WTAP, r2 = r - tap * WTAP;
    int ocl = r2 >> 6, col = r2 & 63;
    int physo = col >> 3, j = col & 7;
    int olog = physo ^ (ocl & 7);
    int ic = olog * 8 + j;
    int oc = octile * 128 + ocl;
    wt[t] = f2b(w[(oc * Cin + ic) * 9 + tap]);
  } else {
    for (int t = threadIdx.x; t < HID; t += 256) {
      float sc = g1[t] * rsqrtf(v1[t] + EPS);
      sc1[t] = sc;
      sh1[t] = b1[t] - m1[t] * sc;
    }
    if (threadIdx.x < CO) {
      int t = threadIdx.x;
      float sc = g3[t] * rsqrtf(v3[t] + EPS);
      sc3[t] = sc;
      sh3[t] = b3[t] - m3[t] * sc;
    }
  }
}

// ---------------------------------------------------------------------------
// P2: x -> xt bf16 swizzled [b][row 58][slot 64][ic 64].
// row = y+1; rows 0 and 57 zero halo; slots 0 and 57..63 zero.
// ---------------------------------------------------------------------------
__global__ __launch_bounds__(256) void k_prep_x(
    const float* __restrict__ x, u16* __restrict__ xt, int b0)
{
  const int row = blockIdx.x;         // 0..57
  const int b = blockIdx.y, gb = b0 + b;
  const int tid = threadIdx.x;
  u16* dst = xt + ((size_t)b * 58 + row) * XTROW;
  if (row == 0 || row == 57) {
    for (int i = tid; i < 2048; i += 256) ((u32*)dst)[i] = 0;
    return;
  }
  const int y = row - 1;
  __shared__ u16 sx[64 * 58];         // [ic][px], pitch 58
  {
    const int ic = tid >> 2, seg = tid & 3;
    const float* xp = x + ((size_t)(gb * Cin + ic) * H + y) * Wd + seg * 14;
    #pragma unroll
    for (int t = 0; t < 14; ++t) sx[ic * 58 + seg * 14 + t] = f2bq(xp[t]);
  }
  __syncthreads();
  #pragma unroll
  for (int it = 0; it < 16; ++it) {
    const int slot = it * 4 + (tid >> 6);   // 0..63
    const int j = tid & 63;
    u16 v = 0;
    if (slot >= 1 && slot <= 56) {
      int ic = (((j >> 3) ^ (slot & 7)) << 3) | (j & 7);
      v = sx[ic * 58 + (slot - 1)];
    }
    dst[slot * 64 + j] = v;           // 128B contiguous per wave-slot
  }
}

// ---------------------------------------------------------------------------
// K1 (r24 = r21 + fast epilogue): fat-wave expand conv MFMA shift-GEMM.
// Block = y-QUAD, 4 waves = 4 rows; wave = full octile 128oc x 64px
// (acc[8][4] = 128 VGPR). Epilogue now uses rcp-silu + v_cvt_pk bf16
// (was ~16 VALU/output -> ~6). Grid 14x32 = 448 blocks @ 2/CU, zero tail.
// ---------------------------------------------------------------------------
__global__ __launch_bounds__(256, 2) void k_expand_mfma(
    const u16* __restrict__ xt, const u16* __restrict__ wt,
    const float* __restrict__ sc1, const float* __restrict__ sh1,
    u16* __restrict__ h, int b0)
{
  (void)b0;
  __shared__ u16 sB[6 * XTROW];      // 49,152 B : xt rows y0..y0+5
  __shared__ u16 sA[2][WTAP];        // 32,768 B
  const int tid = threadIdx.x;
  const int yq = blockIdx.x, b = blockIdx.y;
  const int y0 = yq * 4;
  const int wave = tid >> 6, ln = tid & 63;
  const int lane15 = ln & 15, quad = ln >> 4;

  // prologue staging: sB (6 xt rows = input y0-1..y0+4) + sA[0], all DMA
  {
    const u32* xsrc = (const u32*)(xt + ((size_t)b * 58 + y0) * XTROW);
    #pragma unroll
    for (int it = 0; it < 12; ++it) {
      int chunk = it * 256 + tid;     // 0..3071 16B-chunks
      gload16(xsrc + chunk * 4, (u32*)sB + (chunk & ~63) * 4);
    }
    const u32* wsrc = (const u32*)wt;
    #pragma unroll
    for (int it = 0; it < 4; ++it) {
      int chunk = it * 256 + tid;     // 0..1023
      gload16(wsrc + chunk * 4, (u32*)sA[0] + (chunk & ~63) * 4);
    }
  }
  __syncthreads();   // drains all DMA: sB + sA[0] ready

  const int y = y0 + wave;            // this wave's output row

  for (int octile = 0; octile < 3; ++octile) {
    f32x4 acc[8][4];
    #pragma unroll
    for (int ms = 0; ms < 8; ++ms)
      #pragma unroll
      for (int ns = 0; ns < 4; ++ns) acc[ms][ns] = (f32x4){0.f, 0.f, 0.f, 0.f};

    #pragma unroll
    for (int tap = 0; tap < 9; ++tap) {
      const int step = octile * 9 + tap;       // octile runtime, tap const
      const int buf = (octile + tap) & 1;      // == step & 1 (9 odd)
      const bool pre = (step < 26);

      // T14 issue-early: next slab's weights -> registers
      u32x4 pf0, pf1, pf2, pf3;
      if (pre) {
        const u16* wnx = wt + (size_t)(step + 1) * WTAP;
        pf0 = *(const u32x4*)&wnx[(0 * 256 + tid) * 8];
        pf1 = *(const u32x4*)&wnx[(1 * 256 + tid) * 8];
        pf2 = *(const u32x4*)&wnx[(2 * 256 + tid) * 8];
        pf3 = *(const u32x4*)&wnx[(3 * 256 + tid) * 8];
      }

      constexpr int dyv[9] = {0,0,0,1,1,1,2,2,2};
      constexpr int dxv[9] = {0,1,2,0,1,2,0,1,2};
      const int dy = dyv[tap], dx = dxv[tap];  // compile-time after unroll
      const u16* sAc = sA[buf];
      __builtin_amdgcn_s_setprio(1);
      #pragma unroll
      for (int kk = 0; kk < 2; ++kk) {
        s16x8 bf[4];
        #pragma unroll
        for (int ns = 0; ns < 4; ++ns) {
          int row = wave + dy;                 // 0..5
          int slot = ns * 16 + lane15 + dx;
          int po = (kk * 4 + quad) ^ (slot & 7);
          bf[ns] = *(const s16x8*)&sB[(row * 64 + slot) * 64 + po * 8];
        }
        #pragma unroll
        for (int ms = 0; ms < 8; ++ms) {
          int ocl = ms * 16 + lane15;          // 0..127: full octile
          int po = (kk * 4 + quad) ^ (ocl & 7);
          s16x8 af = *(const s16x8*)&sAc[ocl * 64 + po * 8];
          #pragma unroll
          for (int ns = 0; ns < 4; ++ns)
            acc[ms][ns] = __builtin_amdgcn_mfma_f32_16x16x32_bf16(
                af, bf[ns], acc[ms][ns], 0, 0, 0);
        }
      }
      __builtin_amdgcn_s_setprio(0);

      // T14 write-late: commit prefetched weights to the other buffer.
      if (pre) {
        u16* sAn = sA[buf ^ 1];
        *(u32x4*)&sAn[(0 * 256 + tid) * 8] = pf0;
        *(u32x4*)&sAn[(1 * 256 + tid) * 8] = pf1;
        *(u32x4*)&sAn[(2 * 256 + tid) * 8] = pf2;
        *(u32x4*)&sAn[(3 * 256 + tid) * 8] = pf3;
      }
      __syncthreads();   // publishes sA[buf^1], closes reads of sA[buf]
    }

    // per-octile epilogue: 8 ms x 4 ns x 4 r outputs per wave
    #pragma unroll
    for (int ms = 0; ms < 8; ++ms) {
      int oc0 = octile * 128 + ms * 16 + quad * 4;
      f32x4 sc = *(const f32x4*)&sc1[oc0];
      f32x4 sh = *(const f32x4*)&sh1[oc0];
      float scr[4] = {sc.x, sc.y, sc.z, sc.w};
      float shr[4] = {sh.x, sh.y, sh.z, sh.w};
      #pragma unroll
      for (int ns = 0; ns < 4; ++ns) {
        int xg = ns * 16 + lane15;
        if (xg < Wd) {
          float av[4] = {acc[ms][ns].x, acc[ms][ns].y, acc[ms][ns].z, acc[ms][ns].w};
          #pragma unroll
          for (int r = 0; r < 4; ++r) {
            float val = fsilu(av[r] * scr[r] + shr[r]);
            h[((size_t)(b * HID + oc0 + r) * H + y) * Wd + xg] = f2bq(val);
          }
        }
      }
    }
  }
}

// ---------------------------------------------------------------------------
// K2: depthwise 3x3 + BN2 + SiLU -> d (bf16) + per-(b,c) mean.
// Whole (b,c) plane DMA-staged into LDS once; conv reads from LDS.
// ---------------------------------------------------------------------------
__global__ __launch_bounds__(256) void k_dw(
    const u16* __restrict__ h, const float* __restrict__ wdw,
    const float* __restrict__ g2, const float* __restrict__ b2,
    const float* __restrict__ m2, const float* __restrict__ v2,
    u16* __restrict__ d, float* __restrict__ mean)
{
  __shared__ u32 sdw[1568];           // 56 rows x 28 words = 6272 B
  __shared__ float red[4];
  const int tid = threadIdx.x;
  const int c = blockIdx.x, b = blockIdx.y;
  const u32* hp32 = (const u32*)(h + (size_t)(b * HID + c) * HW);

  // DMA-stage plane: 392 16B chunks (256 + 136)
  gload16(hp32 + tid * 4, sdw + (tid & ~63) * 4);
  if (tid < 136) {
    int chunk = 256 + tid;
    gload16(hp32 + chunk * 4, sdw + (chunk & ~63) * 4);
  }

  f32x2 wv2[9];
  #pragma unroll
  for (int t = 0; t < 9; ++t) {
    float w = wdw[c * 9 + t];
    wv2[t] = (f32x2){w, w};
  }
  const float sc = g2[c] * rsqrtf(v2[c] + EPS);
  const float sh = b2[c] - m2[c] * sc;
  const f32x2 scv = (f32x2){sc, sc}, shv = (f32x2){sh, sh};

  __syncthreads();                    // drains DMA: plane resident in LDS

  float lsum = 0.f;
  if (tid < 224) {
    const int r7 = tid / 28;            // 0..7
    const int wd = tid - r7 * 28;       // 0..27
    const int r0 = r7 * 7;              // first output row
    u32* dp32 = (u32*)(d + (size_t)(b * HID + c) * HW);

    auto loadrow = [&](int rr, f32x2* P) {
      u32 m = 0, c0 = 0, p = 0;
      if (rr >= 0 && rr < 56) {
        const u32* rp = sdw + rr * 28;
        c0 = rp[wd];
        if (wd > 0)  m = rp[wd - 1];
        if (wd < 27) p = rp[wd + 1];
      }
      float f_hm = bfhi(m), f_lc = bflo(c0), f_hc = bfhi(c0), f_lp = bflo(p);
      P[0] = (f32x2){f_hm, f_lc};
      P[1] = (f32x2){f_lc, f_hc};
      P[2] = (f32x2){f_hc, f_lp};
    };

    f32x2 Pa[3], Pb[3], Pc[3];
    loadrow(r0 - 1, Pa);
    loadrow(r0,     Pb);
    f32x2 ls2 = (f32x2){0.f, 0.f};
    #pragma unroll
    for (int i = 0; i < 7; ++i) {
      loadrow(r0 + i + 1, Pc);
      f32x2 s = (f32x2){0.f, 0.f};
      #pragma unroll
      for (int dx = 0; dx < 3; ++dx) s = __builtin_elementwise_fma(Pa[dx], wv2[dx], s);
      #pragma unroll
      for (int dx = 0; dx < 3; ++dx) s = __builtin_elementwise_fma(Pb[dx], wv2[3 + dx], s);
      #pragma unroll
      for (int dx = 0; dx < 3; ++dx) s = __builtin_elementwise_fma(Pc[dx], wv2[6 + dx], s);
      f32x2 t = __builtin_elementwise_fma(s, scv, shv);
      f32x2 val;
      val.x = fsilu(t.x);
      val.y = fsilu(t.y);
      ls2 += val;
      dp32[(r0 + i) * 28 + wd] = pk2b(val.x, val.y);
      #pragma unroll
      for (int q = 0; q < 3; ++q) { Pa[q] = Pb[q]; Pb[q] = Pc[q]; }
    }
    lsum = ls2.x + ls2.y;
  }

  #pragma unroll
  for (int off = 32; off > 0; off >>= 1) lsum += __shfl_down(lsum, off);
  if ((tid & 63) == 0) red[tid >> 6] = lsum;
  __syncthreads();
  if (tid == 0)
    mean[b * HID + c] = (red[0] + red[1] + red[2] + red[3]) * (1.f / 3136.f);
}

// ---------------------------------------------------------------------------
// K3 (r24): SE + pointwise-weight fold -> apk[b]. Grid (8, bc): each part
// recomputes the tiny SE and folds 1/8 of apk (768 f32x4 groups).
// ---------------------------------------------------------------------------
__global__ __launch_bounds__(256) void k_se_fold(
    const float* __restrict__ mean, const float* __restrict__ w1,
    const float* __restrict__ w2, const float* __restrict__ wpw,
    const float* __restrict__ sc3, u16* __restrict__ apk)
{
  __shared__ float smn[HID];
  __shared__ float sps[16 * 17];
  __shared__ float ss1[16];
  __shared__ float ssf[HID];
  const int part = blockIdx.x, b = blockIdx.y, tid = threadIdx.x;
  for (int c = tid; c < HID; c += 256) smn[c] = mean[b * HID + c];
  __syncthreads();
  {
    int r = tid >> 4, j = tid & 15;
    float p = 0.f;
    for (int c = j; c < HID; c += 16) p += smn[c] * w1[r * HID + c];
    sps[r * 17 + j] = p;
  }
  __syncthreads();
  if (tid < 16) {
    float s = 0.f;
    #pragma unroll
    for (int q = 0; q < 16; ++q) s += sps[tid * 17 + q];
    ss1[tid] = fsilu(s);
  }
  __syncthreads();
  for (int c = tid; c < HID; c += 256) {
    float s = 0.f;
    #pragma unroll
    for (int q = 0; q < 16; ++q) s += ss1[q] * w2[c * 16 + q];
    ssf[c] = frcp(1.f + __expf(-s));
  }
  __syncthreads();
  u16* ap = apk + (size_t)b * CO * PWP;
  for (int i = part * 768 + tid; i < (part + 1) * 768; i += 256) {
    int e = i * 4, co = e / 384, k = e - co * 384;
    f32x4 wv = *(const f32x4*)&wpw[e];
    f32x4 sf = *(const f32x4*)&ssf[k];
    float s3 = sc3[co];
    u32x2 pk;
    pk.x = pk2b(wv.x * sf.x * s3, wv.y * sf.y * s3);
    pk.y = pk2b(wv.z * sf.z * s3, wv.w * sf.w * s3);
    *(u32x2*)&ap[co * PWP + k] = pk;
  }
}

// ---------------------------------------------------------------------------
// K4: pointwise MFMA GEMM + setprio around read+MFMA cluster.
// Prologue = 13 DMA loads of precomputed apk.
// ---------------------------------------------------------------------------
__global__ __launch_bounds__(256, 2) void k_pw_mfma(
    const u16* __restrict__ d, const u16* __restrict__ apk,
    const float* __restrict__ sh3,
    const float* __restrict__ x, float* __restrict__ out, int b0)
{
  __shared__ u16 sAw[64 * PWP];     // 50,176 B
  __shared__ u32 dtw[4 * 1024];     // 16,384 B
  const int tid = threadIdx.x;
  const int b = blockIdx.y, gb = b0 + b;
  const int p0 = blockIdx.x * 256;
  const int wave = tid >> 6, ln = tid & 63;
  const int lane15 = ln & 15, quad = ln >> 4;

  // stage A' via DMA: 3136 16B chunks
  {
    const u32* ap = (const u32*)(apk + (size_t)b * CO * PWP);
    #pragma unroll
    for (int i = 0; i < 13; ++i) {
      int chunk = i * 256 + tid;
      if (chunk < 3136)
        gload16(ap + chunk * 4, (u32*)sAw + (chunk & ~63) * 4);
    }
  }
  __syncthreads();

  f32x4 acc[4][4];
  #pragma unroll
  for (int ms = 0; ms < 4; ++ms)
    #pragma unroll
    for (int ns = 0; ns < 4; ++ns) acc[ms][ns] = (f32x4){0.f, 0.f, 0.f, 0.f};

  const int cpair8 = ln >> 3;
  const int pxo = (ln & 7) * 8;
  const int swz = ln & 3;
  const int pbase = p0 + wave * 64;
  u32* mydt = &dtw[wave * 1024];
  const bool ld_ok = (pbase + pxo + 8 <= HW);
  const u16* dbase = d + (size_t)b * HID * HW + pbase + pxo;

  u32x4 pr0[2], pr1[2];
  #pragma unroll
  for (int ci = 0; ci < 2; ++ci) {
    pr0[ci] = (u32x4){0,0,0,0}; pr1[ci] = (u32x4){0,0,0,0};
    if (ld_ok) {
      int c = 2 * (ci * 8 + cpair8);
      const u16* dpp = dbase + (size_t)c * HW;
      pr0[ci] = *(const u32x4*)dpp;
      pr1[ci] = *(const u32x4*)(dpp + HW);
    }
  }

  for (int ks = 0; ks < 12; ++ks) {
    #pragma unroll
    for (int ci = 0; ci < 2; ++ci) {
      int k4 = ci * 2 + (cpair8 >> 2);
      u32* w0 = &mydt[pxo * 16 + ((k4 ^ swz) << 2) + (cpair8 & 3)];
      u32x4 r0 = pr0[ci], r1 = pr1[ci];
      w0[0 * 16] = (r0.x & 0xffffu) | (r1.x << 16);
      w0[1 * 16] = (r0.x >> 16)     | (r1.x & 0xffff0000u);
      w0[2 * 16] = (r0.y & 0xffffu) | (r1.y << 16);
      w0[3 * 16] = (r0.y >> 16)     | (r1.y & 0xffff0000u);
      w0[4 * 16] = (r0.z & 0xffffu) | (r1.z << 16);
      w0[5 * 16] = (r0.z >> 16)     | (r1.z & 0xffff0000u);
      w0[6 * 16] = (r0.w & 0xffffu) | (r1.w << 16);
      w0[7 * 16] = (r0.w >> 16)     | (r1.w & 0xffff0000u);
    }
    if (ks < 11) {
      #pragma unroll
      for (int ci = 0; ci < 2; ++ci) {
        if (ld_ok) {
          int c = (ks + 1) * 32 + 2 * (ci * 8 + cpair8);
          const u16* dpp = dbase + (size_t)c * HW;
          pr0[ci] = *(const u32x4*)dpp;
          pr1[ci] = *(const u32x4*)(dpp + HW);
        }
      }
    }
    const int k0 = ks * 32;
    __builtin_amdgcn_s_setprio(1);
    s16x8 af[4], bf[4];
    #pragma unroll
    for (int ms = 0; ms < 4; ++ms) {
      int ocl = ms * 16 + lane15;
      af[ms] = *(const s16x8*)&sAw[ocl * PWP + k0 + quad * 8];
    }
    #pragma unroll
    for (int ns = 0; ns < 4; ++ns) {
      int pxl = ns * 16 + lane15;
      int p4 = quad ^ ((pxl >> 3) & 3);
      bf[ns] = *(const s16x8*)((const u16*)mydt + pxl * 32 + p4 * 8);
    }
    #pragma unroll
    for (int ms = 0; ms < 4; ++ms)
      #pragma unroll
      for (int ns = 0; ns < 4; ++ns)
        acc[ms][ns] = __builtin_amdgcn_mfma_f32_16x16x32_bf16(
            af[ms], bf[ns], acc[ms][ns], 0, 0, 0);
    __builtin_amdgcn_s_setprio(0);
  }

  #pragma unroll
  for (int ns = 0; ns < 4; ++ns) {
    int p = pbase + ns * 16 + lane15;
    if (p < HW) {
      #pragma unroll
      for (int ms = 0; ms < 4; ++ms) {
        int co0 = ms * 16 + quad * 4;
        float av[4] = {acc[ms][ns].x, acc[ms][ns].y, acc[ms][ns].z, acc[ms][ns].w};
        #pragma unroll
        for (int r = 0; r < 4; ++r) {
          size_t idx = (size_t)(gb * CO + co0 + r) * HW + p;
          out[idx] = av[r] + sh3[co0 + r] + x[idx];
        }
      }
    }
  }
}

// ---------------------------------------------------------------------------
extern "C" void kernel_launch(void* const* d_in, const int* in_sizes, int n_in,
                              void* d_out, int out_size, void* d_ws, size_t ws_size,
                              hipStream_t stream)
{
  (void)in_sizes; (void)n_in; (void)out_size;
  const float* x     = (const float*)d_in[0];
  const float* w_exp = (const float*)d_in[1];
  const float* g1 = (const float*)d_in[2];
  const float* b1 = (const float*)d_in[3];
  const float* m1 = (const float*)d_in[4];
  const float* v1 = (const float*)d_in[5];
  const float* w_dw = (const float*)d_in[6];
  const float* g2 = (const float*)d_in[7];
  const float* b2 = (const float*)d_in[8];
  const float* m2 = (const float*)d_in[9];
  const float* v2 = (const float*)d_in[10];
  const float* w_se1 = (const float*)d_in[11];
  const float* w_se2 = (const float*)d_in[12];
  const float* w_pw  = (const float*)d_in[13];
  const float* g3 = (const float*)d_in[14];
  const float* b3 = (const float*)d_in[15];
  const float* m3 = (const float*)d_in[16];
  const float* v3 = (const float*)d_in[17];

  // per-batch: h + dd (bf16) + mean + xt + apk
  const size_t perB = (size_t)HID * HW * 2 * 2 + HID * 4
                    + (size_t)58 * XTROW * 2 + (size_t)CO * PWP * 2;
  const size_t fixed = 221184 * 2 + HID * 8 + CO * 8;
  int bc = Bn;
  while (bc > 1 && fixed + (size_t)bc * perB > ws_size) bc >>= 1;

  u16* wt = (u16*)d_ws;
  float* sc1 = (float*)(wt + 221184);
  float* sh1 = sc1 + HID;
  float* sc3 = sh1 + HID;
  float* sh3 = sc3 + CO;
  u16* h  = (u16*)(sh3 + CO);
  u16* dd = h + (size_t)bc * HID * HW;
  float* mean = (float*)(dd + (size_t)bc * HID * HW);
  u16* xt = (u16*)(mean + (size_t)bc * HID);
  u16* apk = xt + (size_t)bc * 58 * XTROW;

  k_prep_wbn<<<865, 256, 0, stream>>>(w_exp, g1, b1, m1, v1, g3, b3, m3, v3,
                                      wt, sc1, sh1, sc3, sh3);

  for (int b0 = 0; b0 < Bn; b0 += bc) {
    k_prep_x<<<dim3(58, bc), 256, 0, stream>>>(x, xt, b0);
    k_expand_mfma<<<dim3(14, bc), 256, 0, stream>>>(xt, wt, sc1, sh1, h, b0);
    k_dw<<<dim3(HID, bc), 256, 0, stream>>>(h, w_dw, g2, b2, m2, v2, dd, mean);
    k_se_fold<<<dim3(8, bc), 256, 0, stream>>>(mean, w_se1, w_se2, w_pw, sc3, apk);
    k_pw_mfma<<<dim3(13, bc), 256, 0, stream>>>(dd, apk, sh3,
                                                x, (float*)d_out, b0);
  }
}